// Round 5
// baseline (1272.622 us; speedup 1.0000x reference)
//
#include <hip/hip_runtime.h>
#include <hip/hip_bf16.h>

// Round 5: attn occupancy fix — 4-wave blocks with intra-block key-split.
// Wave w: q-half (w&1), key-half (w>>1) of a 128-key tile; 4 private 8KB
// K/V buffers; partial-O merge through LDS at the end (no-max softmax makes
// the merge a pure add). Per-wave inner loop identical to R4 (VGPR=128).
// GEMMs/cvt unchanged from R4.

#define DIM 768
#define NH 12
#define HD 64
#define NTOK 4096
#define WELEM 589824u      // 768*768
#define TELEM 6291456u     // 2*4096*768

typedef short bf16x8 __attribute__((ext_vector_type(8)));
typedef float floatx4 __attribute__((ext_vector_type(4)));
typedef unsigned short us4 __attribute__((ext_vector_type(4)));

__device__ __forceinline__ float bf2f(unsigned short u) {
    union { unsigned int i; float f; } v; v.i = ((unsigned int)u) << 16; return v.f;
}
__device__ __forceinline__ unsigned short f2bf(float f) {
    union { float f; unsigned int i; } v; v.f = f;
    unsigned int r = v.i + 0x7fffu + ((v.i >> 16) & 1u);
    return (unsigned short)(r >> 16);
}
// pack 2 floats -> 2 bf16 (RNE) in one VGPR via v_perm_b32
__device__ __forceinline__ unsigned int packbf(float a, float b) {
    union { float f; unsigned int i; } ua, ub; ua.f = a; ub.f = b;
    unsigned int ra = ua.i + 0x7fffu + ((ua.i >> 16) & 1u);
    unsigned int rb = ub.i + 0x7fffu + ((ub.i >> 16) & 1u);
    return __builtin_amdgcn_perm(rb, ra, 0x07060302);
}
__device__ __forceinline__ void gl2lds16(const unsigned short* g, unsigned short* l) {
    __builtin_amdgcn_global_load_lds(
        (const __attribute__((address_space(1))) unsigned int*)g,
        (__attribute__((address_space(3))) unsigned int*)l, 16, 0, 0);
}
__device__ __forceinline__ bf16x8 ld8_f32_to_bf16(const float* p) {
    floatx4 f0 = *(const floatx4*)p;
    floatx4 f1 = *(const floatx4*)(p + 4);
    bf16x8 o;
    o[0] = (short)f2bf(f0[0]); o[1] = (short)f2bf(f0[1]);
    o[2] = (short)f2bf(f0[2]); o[3] = (short)f2bf(f0[3]);
    o[4] = (short)f2bf(f1[0]); o[5] = (short)f2bf(f1[1]);
    o[6] = (short)f2bf(f1[2]); o[7] = (short)f2bf(f1[3]);
    return o;
}

#if __has_builtin(__builtin_amdgcn_exp2f)
#define EXPFN(x) __builtin_amdgcn_exp2f(x)
#define QSCALE 0.18033688011f   /* 0.125 * log2(e) */
#else
#define EXPFN(x) __expf(x)
#define QSCALE 0.125f
#endif

// ---------------- fp32 -> bf16 converters ----------------
__global__ __launch_bounds__(256) void cvt_w(
    const float* __restrict__ a, const float* __restrict__ b,
    const float* __restrict__ c, const float* __restrict__ d,
    unsigned short* __restrict__ dst)
{
    size_t i = ((size_t)blockIdx.x * 256 + threadIdx.x) * 8;
    const float* s; size_t off;
    if (i < WELEM)            { s = a; off = i; }
    else if (i < 2u * WELEM)  { s = b; off = i - WELEM; }
    else if (i < 3u * WELEM)  { s = c; off = i - 2u * WELEM; }
    else                      { s = d; off = i - 3u * WELEM; }
    *(bf16x8*)(dst + i) = ld8_f32_to_bf16(s + off);
}

__global__ __launch_bounds__(256) void cvt_in(
    const float* __restrict__ a, const float* __restrict__ b,
    const float* __restrict__ c, unsigned short* __restrict__ dst)
{
    size_t i = ((size_t)blockIdx.x * 256 + threadIdx.x) * 8;
    const float* s; size_t off;
    if (i < TELEM)            { s = a; off = i; }
    else if (i < 2u * TELEM)  { s = b; off = i - TELEM; }
    else                      { s = c; off = i - 2u * TELEM; }
    *(bf16x8*)(dst + i) = ld8_f32_to_bf16(s + off);
}

// ---------------------------------------------------------------------------
// 128x128 tile GEMM, BK=64, XOR chunk swizzle (unchanged from R3/R4).
// ---------------------------------------------------------------------------
template <int A_IS_BF16>
__device__ __forceinline__ void gemm128(
    const void* __restrict__ Av, const unsigned short* __restrict__ W,
    const float* __restrict__ bias, void* __restrict__ Cv,
    int has_bias, int do_gelu, int trans, int out_f32)
{
    __shared__ unsigned short As[128 * 64];
    __shared__ unsigned short Bs[128 * 64];
    const int m0 = blockIdx.x * 128, n0 = blockIdx.y * 128;
    const int tid = threadIdx.x;
    const int w = tid >> 6, l = tid & 63;
    const int g = l >> 4, r16 = l & 15;
    const int wm = w >> 1, wn = w & 1;
    const int ro = l >> 3, c = l & 7;
    const int cswz = ((c ^ ro) & 7) * 8;

    floatx4 acc[4][4];
#pragma unroll
    for (int i = 0; i < 4; i++)
#pragma unroll
        for (int j = 0; j < 4; j++) acc[i][j] = (floatx4){0.f, 0.f, 0.f, 0.f};

    for (int k0 = 0; k0 < DIM; k0 += 64) {
#pragma unroll
        for (int q = 0; q < 4; q++) {
            int rbase = w * 32 + q * 8;
            if (A_IS_BF16) {
                gl2lds16((const unsigned short*)Av + (size_t)(m0 + rbase + ro) * DIM + k0 + cswz,
                         As + rbase * 64);
            } else {
                bf16x8 a = ld8_f32_to_bf16((const float*)Av + (size_t)(m0 + rbase + ro) * DIM + k0 + c * 8);
                *(bf16x8*)(As + (rbase + ro) * 64 + cswz) = a;
            }
            gl2lds16(W + (size_t)(n0 + rbase + ro) * DIM + k0 + cswz, Bs + rbase * 64);
        }
        __syncthreads();

#pragma unroll
        for (int kk = 0; kk < 2; kk++) {
            bf16x8 af[4], bfr[4];
            int x = r16 & 7;
#pragma unroll
            for (int i = 0; i < 4; i++)
                af[i] = *(const bf16x8*)(As + (wm * 64 + i * 16 + r16) * 64 + (((kk * 4 + g) ^ x) * 8));
#pragma unroll
            for (int j = 0; j < 4; j++)
                bfr[j] = *(const bf16x8*)(Bs + (wn * 64 + j * 16 + r16) * 64 + (((kk * 4 + g) ^ x) * 8));
#pragma unroll
            for (int i = 0; i < 4; i++)
#pragma unroll
                for (int j = 0; j < 4; j++)
                    acc[i][j] = __builtin_amdgcn_mfma_f32_16x16x32_bf16(af[i], bfr[j], acc[i][j], 0, 0, 0);
        }
        __syncthreads();
    }

    if (trans) {
        unsigned short* C = (unsigned short*)Cv;
#pragma unroll
        for (int i = 0; i < 4; i++) {
            int m = m0 + wm * 64 + i * 16 + g * 4;
            int b = m >> 12, tloc = m & 4095;
#pragma unroll
            for (int j = 0; j < 4; j++) {
                int n = n0 + wn * 64 + j * 16 + r16;
                int h = n >> 6, d = n & 63;
                us4 pk;
                pk[0] = f2bf(acc[i][j][0]); pk[1] = f2bf(acc[i][j][1]);
                pk[2] = f2bf(acc[i][j][2]); pk[3] = f2bf(acc[i][j][3]);
                *(us4*)(C + ((size_t)(b * NH + h) * 64 + d) * NTOK + tloc) = pk;
            }
        }
    } else {
#pragma unroll
        for (int i = 0; i < 4; i++)
#pragma unroll
            for (int j = 0; j < 4; j++) {
                int n = n0 + wn * 64 + j * 16 + r16;
                float bv = has_bias ? bias[n] : 0.f;
#pragma unroll
                for (int r = 0; r < 4; r++) {
                    int m = m0 + wm * 64 + i * 16 + g * 4 + r;
                    float v = acc[i][j][r] + bv;
                    if (do_gelu) v = 0.5f * v * (1.f + erff(v * 0.70710678118f));
                    if (out_f32) ((float*)Cv)[(size_t)m * DIM + n] = v;
                    else ((unsigned short*)Cv)[(size_t)m * DIM + n] = f2bf(v);
                }
            }
    }
}

template <int A_IS_BF16>
__global__ __launch_bounds__(256) void qkv_gemm(
    const void* __restrict__ q_in, const void* __restrict__ k_in,
    const void* __restrict__ v_in,
    const unsigned short* __restrict__ Wq, const unsigned short* __restrict__ Wk,
    const unsigned short* __restrict__ Wv, const float* __restrict__ bk,
    unsigned short* __restrict__ Qo, unsigned short* __restrict__ Ko,
    unsigned short* __restrict__ Vto)
{
    int z = blockIdx.z;
    const void* A = (z == 0) ? q_in : (z == 1) ? k_in : v_in;
    const unsigned short* W = (z == 0) ? Wq : (z == 1) ? Wk : Wv;
    unsigned short* C = (z == 0) ? Qo : (z == 1) ? Ko : Vto;
    gemm128<A_IS_BF16>(A, W, bk, C, z == 1, z == 1, z == 2, 0);
}

__global__ __launch_bounds__(256) void out_gemm(
    const unsigned short* __restrict__ X, const unsigned short* __restrict__ Wp,
    const float* __restrict__ bp, float* __restrict__ out)
{
    gemm128<1>(X, Wp, bp, out, 1, 0, 0, 1);
}

// ---------------------------------------------------------------------------
// Flash attention R5: 4 waves/block, intra-block key-split.
// Wave w: q-half (w&1), key-half (w>>1). 128-key tile = 4 x 8KB buffers,
// each staged by one wave. S^T/κ/PV structure identical to R4 per-wave.
// End: upper waves write partial O^T (fp32) + lsum to LDS; lower waves add.
// ---------------------------------------------------------------------------
__device__ __forceinline__ int swzf(int R) { return (R & 7) ^ ((R >> 2) & 6); }

__global__ __launch_bounds__(256, 4) void attn_kernel(
    const unsigned short* __restrict__ Q, const unsigned short* __restrict__ K,
    const unsigned short* __restrict__ Vt, unsigned short* __restrict__ X)
{
    __shared__ unsigned short Smem[4 * 64 * 64];   // Ks0|Vs0|Ks1|Vs1 (32 KB)
    __shared__ float Lx[2][64];
    unsigned short* Ks0 = Smem;
    unsigned short* Vs0 = Smem + 4096;
    unsigned short* Ks1 = Smem + 8192;
    unsigned short* Vs1 = Smem + 12288;

    const int qt = blockIdx.x, bh = blockIdx.y;
    const int b = bh / NH, h = bh % NH;
    const int tid = threadIdx.x;
    const int w = tid >> 6, l = tid & 63;
    const int g = l >> 4, r16 = l & 15;
    const int wq = w & 1, wk = w >> 1;
    const int tokbase = b * NTOK;

    // Q B-fragments for this wave's 64 q-rows, pre-scaled
    bf16x8 qfr[4][2];
#pragma unroll
    for (int qfi = 0; qfi < 4; qfi++) {
        int qrow = tokbase + qt * 128 + wq * 64 + qfi * 16 + r16;
#pragma unroll
        for (int kk = 0; kk < 2; kk++) {
            bf16x8 t = *(const bf16x8*)(Q + (size_t)qrow * DIM + h * HD + kk * 32 + g * 8);
#pragma unroll
            for (int j = 0; j < 8; j++)
                t[j] = (short)f2bf(bf2f((unsigned short)t[j]) * QSCALE);
            qfr[qfi][kk] = t;
        }
    }

    // loop-invariant frag offsets into this wave's buffers
    const unsigned short* myKs = wk ? Ks1 : Ks0;
    const unsigned short* myVs = wk ? Vs1 : Vs0;
    int koff[4][2], voff[4][2];
#pragma unroll
    for (int ct = 0; ct < 4; ct++) {
        int krow = (ct >> 1) * 32 + (r16 >> 2) * 8 + (ct & 1) * 4 + (r16 & 3);
#pragma unroll
        for (int kk = 0; kk < 2; kk++)
            koff[ct][kk] = krow * 64 + (((kk * 4 + g) ^ swzf(krow)) * 8);
    }
#pragma unroll
    for (int dt = 0; dt < 4; dt++) {
        int vrow = dt * 16 + r16;
#pragma unroll
        for (int c = 0; c < 2; c++)
            voff[dt][c] = vrow * 64 + (((c * 4 + g) ^ swzf(vrow)) * 8);
    }

    // staging: w0->Ks0(keys 0-63), w1->Vs0, w2->Ks1(keys 64-127), w3->Vs1
    unsigned short* sdst = (w == 0) ? Ks0 : (w == 1) ? Vs0 : (w == 2) ? Ks1 : Vs1;
    const int isV = w & 1;
    const int sstride = isV ? NTOK : DIM;
    int soff[8];
    const int srl = l >> 3, scc = l & 7;
#pragma unroll
    for (int i = 0; i < 8; i++) {
        int row = i * 8 + srl;
        soff[i] = row * sstride + ((scc ^ swzf(row)) * 8);
    }
    const unsigned short* Kbase = K + (size_t)tokbase * DIM + h * HD;
    const unsigned short* Vbase = Vt + (size_t)bh * 64 * NTOK;

    floatx4 o[4][4];
#pragma unroll
    for (int qfi = 0; qfi < 4; qfi++)
#pragma unroll
        for (int dt = 0; dt < 4; dt++) o[qfi][dt] = (floatx4){0.f, 0.f, 0.f, 0.f};
    float lsum[4] = {0.f, 0.f, 0.f, 0.f};

    for (int kt = 0; kt < NTOK / 128; kt++) {
        int keyoff = kt * 128 + (w >> 1) * 64;
        const unsigned short* p = isV ? (Vbase + keyoff)
                                      : (Kbase + (size_t)keyoff * DIM);
#pragma unroll
        for (int i = 0; i < 8; i++) gl2lds16(p + soff[i], sdst + i * 512);
        __syncthreads();

        bf16x8 kr[4][2], vr[4][2];
#pragma unroll
        for (int ct = 0; ct < 4; ct++)
#pragma unroll
            for (int kk = 0; kk < 2; kk++)
                kr[ct][kk] = *(const bf16x8*)(myKs + koff[ct][kk]);
#pragma unroll
        for (int dt = 0; dt < 4; dt++)
#pragma unroll
            for (int c = 0; c < 2; c++)
                vr[dt][c] = *(const bf16x8*)(myVs + voff[dt][c]);

#pragma unroll
        for (int qfi = 0; qfi < 4; qfi++) {
            floatx4 s[4];
#pragma unroll
            for (int ct = 0; ct < 4; ct++) {
                floatx4 z = (floatx4){0.f, 0.f, 0.f, 0.f};
                z = __builtin_amdgcn_mfma_f32_16x16x32_bf16(kr[ct][0], qfr[qfi][0], z, 0, 0, 0);
                s[ct] = __builtin_amdgcn_mfma_f32_16x16x32_bf16(kr[ct][1], qfr[qfi][1], z, 0, 0, 0);
            }
            float ls = 0.f;
#pragma unroll
            for (int ct = 0; ct < 4; ct++)
#pragma unroll
                for (int r = 0; r < 4; r++) {
                    float p2 = EXPFN(s[ct][r]);
                    s[ct][r] = p2;
                    ls += p2;
                }
            lsum[qfi] += ls;

            unsigned int pk[4][2];
#pragma unroll
            for (int ct = 0; ct < 4; ct++) {
                pk[ct][0] = packbf(s[ct][0], s[ct][1]);
                pk[ct][1] = packbf(s[ct][2], s[ct][3]);
            }
#pragma unroll
            for (int c = 0; c < 2; c++) {
                union { unsigned int u[4]; bf16x8 v; } bf;
                bf.u[0] = pk[2 * c][0]; bf.u[1] = pk[2 * c][1];
                bf.u[2] = pk[2 * c + 1][0]; bf.u[3] = pk[2 * c + 1][1];
#pragma unroll
                for (int dt = 0; dt < 4; dt++)
                    o[qfi][dt] = __builtin_amdgcn_mfma_f32_16x16x32_bf16(vr[dt][c], bf.v, o[qfi][dt], 0, 0, 0);
            }
        }
        __syncthreads();
    }

    // in-wave denominator reduce (across the 4 quads)
#pragma unroll
    for (int qfi = 0; qfi < 4; qfi++) {
        lsum[qfi] += __shfl_xor(lsum[qfi], 16, 64);
        lsum[qfi] += __shfl_xor(lsum[qfi], 32, 64);
    }

    // merge key-halves: upper waves (wk=1) publish partials, lower waves add
    float* Opart = (float*)Smem;   // 2 x 16KB regions (q-half 0 / 1)
    if (w >= 2) {
        float* P = Opart + wq * 4096;
#pragma unroll
        for (int qfi = 0; qfi < 4; qfi++)
#pragma unroll
            for (int dt = 0; dt < 4; dt++)
                *(floatx4*)(P + (qfi * 4 + dt) * 256 + l * 4) = o[qfi][dt];
        if (g == 0)
#pragma unroll
            for (int qfi = 0; qfi < 4; qfi++)
                Lx[wq][qfi * 16 + r16] = lsum[qfi];
    }
    __syncthreads();
    if (w < 2) {
        const float* P = Opart + wq * 4096;
#pragma unroll
        for (int qfi = 0; qfi < 4; qfi++) {
#pragma unroll
            for (int dt = 0; dt < 4; dt++)
                o[qfi][dt] += *(const floatx4*)(P + (qfi * 4 + dt) * 256 + l * 4);
            lsum[qfi] += Lx[wq][qfi * 16 + r16];
        }
        // O^T C-layout: row = d (g*4+reg), col = q (r16) -> 8B stores
#pragma unroll
        for (int qfi = 0; qfi < 4; qfi++) {
            float inv = 1.f / lsum[qfi];
            int tok = tokbase + qt * 128 + wq * 64 + qfi * 16 + r16;
#pragma unroll
            for (int dt = 0; dt < 4; dt++) {
                us4 pkv;
                pkv[0] = f2bf(o[qfi][dt][0] * inv);
                pkv[1] = f2bf(o[qfi][dt][1] * inv);
                pkv[2] = f2bf(o[qfi][dt][2] * inv);
                pkv[3] = f2bf(o[qfi][dt][3] * inv);
                *(us4*)(X + (size_t)tok * DIM + h * HD + dt * 16 + g * 4) = pkv;
            }
        }
    }
}

extern "C" void kernel_launch(void* const* d_in, const int* in_sizes, int n_in,
                              void* d_out, int out_size, void* d_ws, size_t ws_size,
                              hipStream_t stream) {
    const float* query = (const float*)d_in[0];
    const float* key   = (const float*)d_in[1];
    const float* value = (const float*)d_in[2];
    const float* Wq    = (const float*)d_in[3];
    const float* Wk    = (const float*)d_in[4];
    const float* bk    = (const float*)d_in[5];
    const float* Wv    = (const float*)d_in[6];
    const float* Wp    = (const float*)d_in[7];
    const float* bp    = (const float*)d_in[8];
    float* out = (float*)d_out;

    unsigned short* ws = (unsigned short*)d_ws;
    unsigned short* Wqb = ws;
    unsigned short* Wkb = Wqb + WELEM;
    unsigned short* Wvb = Wkb + WELEM;
    unsigned short* Wpb = Wvb + WELEM;
    unsigned short* Qp  = Wpb + WELEM;
    unsigned short* Kp  = Qp + TELEM;
    unsigned short* Vtp = Kp + TELEM;
    unsigned short* Xp  = Vtp + TELEM;
    unsigned short* Qbf = Xp + TELEM;
    unsigned short* Kbf = Qbf + TELEM;
    unsigned short* Vbf = Kbf + TELEM;

    const size_t need_full = ((size_t)4 * WELEM + 7 * TELEM) * 2;
    const bool full = ws_size >= need_full;

    cvt_w<<<dim3(4 * WELEM / 8 / 256), 256, 0, stream>>>(Wq, Wk, Wv, Wp, Wqb);
    if (full) {
        cvt_in<<<dim3(3 * TELEM / 8 / 256), 256, 0, stream>>>(query, key, value, Qbf);
        qkv_gemm<1><<<dim3(64, 6, 3), 256, 0, stream>>>(Qbf, Kbf, Vbf, Wqb, Wkb, Wvb, bk, Qp, Kp, Vtp);
    } else {
        qkv_gemm<0><<<dim3(64, 6, 3), 256, 0, stream>>>(query, key, value, Wqb, Wkb, Wvb, bk, Qp, Kp, Vtp);
    }
    attn_kernel<<<dim3(32, 24), 256, 0, stream>>>(Qp, Kp, Vtp, Xp);
    out_gemm<<<dim3(64, 6), 256, 0, stream>>>(Xp, Wpb, bp, out);
}

// Round 6
// 367.154 us; speedup vs baseline: 3.4662x; 3.4662x over previous
//
#include <hip/hip_runtime.h>
#include <hip/hip_bf16.h>

// Round 6: revert attn to R4 per-wave structure (128 VGPR, no spill);
// raise occupancy via cross-block key-split (S=2, blockIdx.z) with fp32
// partial O/denominator in ws + elementwise merge kernel. R5's
// launch_bounds(256,4) spill (5.1 GB scratch traffic) is the anti-pattern.

#define DIM 768
#define NH 12
#define HD 64
#define NTOK 4096
#define WELEM 589824u      // 768*768
#define TELEM 6291456u     // 2*4096*768
#define LELEM 196608u      // 2*24*4096 (split x bh x tokloc)

typedef short bf16x8 __attribute__((ext_vector_type(8)));
typedef float floatx4 __attribute__((ext_vector_type(4)));
typedef unsigned short us4 __attribute__((ext_vector_type(4)));

__device__ __forceinline__ float bf2f(unsigned short u) {
    union { unsigned int i; float f; } v; v.i = ((unsigned int)u) << 16; return v.f;
}
__device__ __forceinline__ unsigned short f2bf(float f) {
    union { float f; unsigned int i; } v; v.f = f;
    unsigned int r = v.i + 0x7fffu + ((v.i >> 16) & 1u);
    return (unsigned short)(r >> 16);
}
__device__ __forceinline__ unsigned int packbf(float a, float b) {
    union { float f; unsigned int i; } ua, ub; ua.f = a; ub.f = b;
    unsigned int ra = ua.i + 0x7fffu + ((ua.i >> 16) & 1u);
    unsigned int rb = ub.i + 0x7fffu + ((ub.i >> 16) & 1u);
    return __builtin_amdgcn_perm(rb, ra, 0x07060302);
}
__device__ __forceinline__ void gl2lds16(const unsigned short* g, unsigned short* l) {
    __builtin_amdgcn_global_load_lds(
        (const __attribute__((address_space(1))) unsigned int*)g,
        (__attribute__((address_space(3))) unsigned int*)l, 16, 0, 0);
}
__device__ __forceinline__ bf16x8 ld8_f32_to_bf16(const float* p) {
    floatx4 f0 = *(const floatx4*)p;
    floatx4 f1 = *(const floatx4*)(p + 4);
    bf16x8 o;
    o[0] = (short)f2bf(f0[0]); o[1] = (short)f2bf(f0[1]);
    o[2] = (short)f2bf(f0[2]); o[3] = (short)f2bf(f0[3]);
    o[4] = (short)f2bf(f1[0]); o[5] = (short)f2bf(f1[1]);
    o[6] = (short)f2bf(f1[2]); o[7] = (short)f2bf(f1[3]);
    return o;
}

#if __has_builtin(__builtin_amdgcn_exp2f)
#define EXPFN(x) __builtin_amdgcn_exp2f(x)
#define QSCALE 0.18033688011f   /* 0.125 * log2(e) */
#else
#define EXPFN(x) __expf(x)
#define QSCALE 0.125f
#endif

// ---------------- fp32 -> bf16 converters ----------------
__global__ __launch_bounds__(256) void cvt_w(
    const float* __restrict__ a, const float* __restrict__ b,
    const float* __restrict__ c, const float* __restrict__ d,
    unsigned short* __restrict__ dst)
{
    size_t i = ((size_t)blockIdx.x * 256 + threadIdx.x) * 8;
    const float* s; size_t off;
    if (i < WELEM)            { s = a; off = i; }
    else if (i < 2u * WELEM)  { s = b; off = i - WELEM; }
    else if (i < 3u * WELEM)  { s = c; off = i - 2u * WELEM; }
    else                      { s = d; off = i - 3u * WELEM; }
    *(bf16x8*)(dst + i) = ld8_f32_to_bf16(s + off);
}

__global__ __launch_bounds__(256) void cvt_in(
    const float* __restrict__ a, const float* __restrict__ b,
    const float* __restrict__ c, unsigned short* __restrict__ dst)
{
    size_t i = ((size_t)blockIdx.x * 256 + threadIdx.x) * 8;
    const float* s; size_t off;
    if (i < TELEM)            { s = a; off = i; }
    else if (i < 2u * TELEM)  { s = b; off = i - TELEM; }
    else                      { s = c; off = i - 2u * TELEM; }
    *(bf16x8*)(dst + i) = ld8_f32_to_bf16(s + off);
}

// ---------------------------------------------------------------------------
// 128x128 tile GEMM, BK=64, XOR chunk swizzle (unchanged from R3/R4).
// ---------------------------------------------------------------------------
template <int A_IS_BF16>
__device__ __forceinline__ void gemm128(
    const void* __restrict__ Av, const unsigned short* __restrict__ W,
    const float* __restrict__ bias, void* __restrict__ Cv,
    int has_bias, int do_gelu, int trans, int out_f32)
{
    __shared__ unsigned short As[128 * 64];
    __shared__ unsigned short Bs[128 * 64];
    const int m0 = blockIdx.x * 128, n0 = blockIdx.y * 128;
    const int tid = threadIdx.x;
    const int w = tid >> 6, l = tid & 63;
    const int g = l >> 4, r16 = l & 15;
    const int wm = w >> 1, wn = w & 1;
    const int ro = l >> 3, c = l & 7;
    const int cswz = ((c ^ ro) & 7) * 8;

    floatx4 acc[4][4];
#pragma unroll
    for (int i = 0; i < 4; i++)
#pragma unroll
        for (int j = 0; j < 4; j++) acc[i][j] = (floatx4){0.f, 0.f, 0.f, 0.f};

    for (int k0 = 0; k0 < DIM; k0 += 64) {
#pragma unroll
        for (int q = 0; q < 4; q++) {
            int rbase = w * 32 + q * 8;
            if (A_IS_BF16) {
                gl2lds16((const unsigned short*)Av + (size_t)(m0 + rbase + ro) * DIM + k0 + cswz,
                         As + rbase * 64);
            } else {
                bf16x8 a = ld8_f32_to_bf16((const float*)Av + (size_t)(m0 + rbase + ro) * DIM + k0 + c * 8);
                *(bf16x8*)(As + (rbase + ro) * 64 + cswz) = a;
            }
            gl2lds16(W + (size_t)(n0 + rbase + ro) * DIM + k0 + cswz, Bs + rbase * 64);
        }
        __syncthreads();

#pragma unroll
        for (int kk = 0; kk < 2; kk++) {
            bf16x8 af[4], bfr[4];
            int x = r16 & 7;
#pragma unroll
            for (int i = 0; i < 4; i++)
                af[i] = *(const bf16x8*)(As + (wm * 64 + i * 16 + r16) * 64 + (((kk * 4 + g) ^ x) * 8));
#pragma unroll
            for (int j = 0; j < 4; j++)
                bfr[j] = *(const bf16x8*)(Bs + (wn * 64 + j * 16 + r16) * 64 + (((kk * 4 + g) ^ x) * 8));
#pragma unroll
            for (int i = 0; i < 4; i++)
#pragma unroll
                for (int j = 0; j < 4; j++)
                    acc[i][j] = __builtin_amdgcn_mfma_f32_16x16x32_bf16(af[i], bfr[j], acc[i][j], 0, 0, 0);
        }
        __syncthreads();
    }

    if (trans) {
        unsigned short* C = (unsigned short*)Cv;
#pragma unroll
        for (int i = 0; i < 4; i++) {
            int m = m0 + wm * 64 + i * 16 + g * 4;
            int b = m >> 12, tloc = m & 4095;
#pragma unroll
            for (int j = 0; j < 4; j++) {
                int n = n0 + wn * 64 + j * 16 + r16;
                int h = n >> 6, d = n & 63;
                us4 pk;
                pk[0] = f2bf(acc[i][j][0]); pk[1] = f2bf(acc[i][j][1]);
                pk[2] = f2bf(acc[i][j][2]); pk[3] = f2bf(acc[i][j][3]);
                *(us4*)(C + ((size_t)(b * NH + h) * 64 + d) * NTOK + tloc) = pk;
            }
        }
    } else {
#pragma unroll
        for (int i = 0; i < 4; i++)
#pragma unroll
            for (int j = 0; j < 4; j++) {
                int n = n0 + wn * 64 + j * 16 + r16;
                float bv = has_bias ? bias[n] : 0.f;
#pragma unroll
                for (int r = 0; r < 4; r++) {
                    int m = m0 + wm * 64 + i * 16 + g * 4 + r;
                    float v = acc[i][j][r] + bv;
                    if (do_gelu) v = 0.5f * v * (1.f + erff(v * 0.70710678118f));
                    if (out_f32) ((float*)Cv)[(size_t)m * DIM + n] = v;
                    else ((unsigned short*)Cv)[(size_t)m * DIM + n] = f2bf(v);
                }
            }
    }
}

template <int A_IS_BF16>
__global__ __launch_bounds__(256) void qkv_gemm(
    const void* __restrict__ q_in, const void* __restrict__ k_in,
    const void* __restrict__ v_in,
    const unsigned short* __restrict__ Wq, const unsigned short* __restrict__ Wk,
    const unsigned short* __restrict__ Wv, const float* __restrict__ bk,
    unsigned short* __restrict__ Qo, unsigned short* __restrict__ Ko,
    unsigned short* __restrict__ Vto)
{
    int z = blockIdx.z;
    const void* A = (z == 0) ? q_in : (z == 1) ? k_in : v_in;
    const unsigned short* W = (z == 0) ? Wq : (z == 1) ? Wk : Wv;
    unsigned short* C = (z == 0) ? Qo : (z == 1) ? Ko : Vto;
    gemm128<A_IS_BF16>(A, W, bk, C, z == 1, z == 1, z == 2, 0);
}

__global__ __launch_bounds__(256) void out_gemm(
    const unsigned short* __restrict__ X, const unsigned short* __restrict__ Wp,
    const float* __restrict__ bp, float* __restrict__ out)
{
    gemm128<1>(X, Wp, bp, out, 1, 0, 0, 1);
}

// ---------------------------------------------------------------------------
// Flash attention R6 = R4 body + SPLIT template. SPLIT=2: blockIdx.z picks a
// 2048-key half; partial O^T (fp32) + partial lsum go to ws; merge kernel
// finishes. SPLIT=1: identical to R4 (fallback when ws is tight).
// ---------------------------------------------------------------------------
__device__ __forceinline__ int swzf(int R) { return (R & 7) ^ ((R >> 2) & 6); }

template <int SPLIT>
__global__ __launch_bounds__(128, 2) void attn_kernel(
    const unsigned short* __restrict__ Q, const unsigned short* __restrict__ K,
    const unsigned short* __restrict__ Vt, unsigned short* __restrict__ X,
    float* __restrict__ Op, float* __restrict__ Lp)
{
    __shared__ unsigned short Ks[64 * 64];
    __shared__ unsigned short Vs[64 * 64];
    const int qt = blockIdx.x, bh = blockIdx.y;
    const int z = (SPLIT == 2) ? blockIdx.z : 0;
    const int b = bh / NH, h = bh % NH;
    const int tid = threadIdx.x;
    const int w = tid >> 6, l = tid & 63;
    const int g = l >> 4, r16 = l & 15;
    const int tokbase = b * NTOK;

    bf16x8 qfr[4][2];
#pragma unroll
    for (int qfi = 0; qfi < 4; qfi++) {
        int qrow = tokbase + qt * 128 + w * 64 + qfi * 16 + r16;
#pragma unroll
        for (int kk = 0; kk < 2; kk++) {
            bf16x8 t = *(const bf16x8*)(Q + (size_t)qrow * DIM + h * HD + kk * 32 + g * 8);
#pragma unroll
            for (int j = 0; j < 8; j++)
                t[j] = (short)f2bf(bf2f((unsigned short)t[j]) * QSCALE);
            qfr[qfi][kk] = t;
        }
    }

    int koff[4][2], voff[4][2];
#pragma unroll
    for (int ct = 0; ct < 4; ct++) {
        int krow = (ct >> 1) * 32 + (r16 >> 2) * 8 + (ct & 1) * 4 + (r16 & 3);
#pragma unroll
        for (int kk = 0; kk < 2; kk++)
            koff[ct][kk] = krow * 64 + (((kk * 4 + g) ^ swzf(krow)) * 8);
    }
#pragma unroll
    for (int dt = 0; dt < 4; dt++) {
        int vrow = dt * 16 + r16;
#pragma unroll
        for (int c = 0; c < 2; c++)
            voff[dt][c] = vrow * 64 + (((c * 4 + g) ^ swzf(vrow)) * 8);
    }

    int soff[8];
    const int srl = l >> 3, scc = l & 7;
    const int sstride = (w == 0) ? DIM : NTOK;
#pragma unroll
    for (int i = 0; i < 8; i++) {
        int row = i * 8 + srl;
        soff[i] = row * sstride + ((scc ^ swzf(row)) * 8);
    }
    const unsigned short* Kbase = K + (size_t)tokbase * DIM + h * HD;
    const unsigned short* Vbase = Vt + (size_t)bh * 64 * NTOK;
    const int key0 = z * (NTOK / SPLIT);

    floatx4 o[4][4];
#pragma unroll
    for (int qfi = 0; qfi < 4; qfi++)
#pragma unroll
        for (int dt = 0; dt < 4; dt++) o[qfi][dt] = (floatx4){0.f, 0.f, 0.f, 0.f};
    float lsum[4] = {0.f, 0.f, 0.f, 0.f};

    for (int kt = 0; kt < NTOK / (64 * SPLIT); kt++) {
        int keyg = key0 + kt * 64;
        if (w == 0) {
            const unsigned short* p = Kbase + (size_t)keyg * DIM;
#pragma unroll
            for (int i = 0; i < 8; i++) gl2lds16(p + soff[i], Ks + i * 512);
        } else {
            const unsigned short* p = Vbase + keyg;
#pragma unroll
            for (int i = 0; i < 8; i++) gl2lds16(p + soff[i], Vs + i * 512);
        }
        __syncthreads();

        bf16x8 kr[4][2], vr[4][2];
#pragma unroll
        for (int ct = 0; ct < 4; ct++)
#pragma unroll
            for (int kk = 0; kk < 2; kk++)
                kr[ct][kk] = *(const bf16x8*)(Ks + koff[ct][kk]);
#pragma unroll
        for (int dt = 0; dt < 4; dt++)
#pragma unroll
            for (int c = 0; c < 2; c++)
                vr[dt][c] = *(const bf16x8*)(Vs + voff[dt][c]);

#pragma unroll
        for (int qfi = 0; qfi < 4; qfi++) {
            floatx4 s[4];
#pragma unroll
            for (int ct = 0; ct < 4; ct++) {
                floatx4 zz = (floatx4){0.f, 0.f, 0.f, 0.f};
                zz = __builtin_amdgcn_mfma_f32_16x16x32_bf16(kr[ct][0], qfr[qfi][0], zz, 0, 0, 0);
                s[ct] = __builtin_amdgcn_mfma_f32_16x16x32_bf16(kr[ct][1], qfr[qfi][1], zz, 0, 0, 0);
            }
            float ls = 0.f;
#pragma unroll
            for (int ct = 0; ct < 4; ct++)
#pragma unroll
                for (int r = 0; r < 4; r++) {
                    float p2 = EXPFN(s[ct][r]);
                    s[ct][r] = p2;
                    ls += p2;
                }
            lsum[qfi] += ls;

            unsigned int pk[4][2];
#pragma unroll
            for (int ct = 0; ct < 4; ct++) {
                pk[ct][0] = packbf(s[ct][0], s[ct][1]);
                pk[ct][1] = packbf(s[ct][2], s[ct][3]);
            }
#pragma unroll
            for (int c = 0; c < 2; c++) {
                union { unsigned int u[4]; bf16x8 v; } bf;
                bf.u[0] = pk[2 * c][0]; bf.u[1] = pk[2 * c][1];
                bf.u[2] = pk[2 * c + 1][0]; bf.u[3] = pk[2 * c + 1][1];
#pragma unroll
                for (int dt = 0; dt < 4; dt++)
                    o[qfi][dt] = __builtin_amdgcn_mfma_f32_16x16x32_bf16(vr[dt][c], bf.v, o[qfi][dt], 0, 0, 0);
            }
        }
        __syncthreads();
    }

#pragma unroll
    for (int qfi = 0; qfi < 4; qfi++) {
        lsum[qfi] += __shfl_xor(lsum[qfi], 16, 64);
        lsum[qfi] += __shfl_xor(lsum[qfi], 32, 64);
    }

    if (SPLIT == 2) {
        // partial O^T (fp32) + partial denominator
#pragma unroll
        for (int qfi = 0; qfi < 4; qfi++) {
            int tok = tokbase + qt * 128 + w * 64 + qfi * 16 + r16;
#pragma unroll
            for (int dt = 0; dt < 4; dt++)
                *(floatx4*)(Op + (size_t)z * TELEM + (size_t)tok * DIM + h * HD + dt * 16 + g * 4) = o[qfi][dt];
            if (g == 0)
                Lp[((size_t)z * 24 + bh) * 4096 + qt * 128 + w * 64 + qfi * 16 + r16] = lsum[qfi];
        }
    } else {
#pragma unroll
        for (int qfi = 0; qfi < 4; qfi++) {
            float inv = 1.f / lsum[qfi];
            int tok = tokbase + qt * 128 + w * 64 + qfi * 16 + r16;
#pragma unroll
            for (int dt = 0; dt < 4; dt++) {
                us4 pkv;
                pkv[0] = f2bf(o[qfi][dt][0] * inv);
                pkv[1] = f2bf(o[qfi][dt][1] * inv);
                pkv[2] = f2bf(o[qfi][dt][2] * inv);
                pkv[3] = f2bf(o[qfi][dt][3] * inv);
                *(us4*)(X + (size_t)tok * DIM + h * HD + dt * 16 + g * 4) = pkv;
            }
        }
    }
}

// merge: X = (O0 + O1) / (l0 + l1), bf16 out
__global__ __launch_bounds__(256) void merge_kernel(
    const float* __restrict__ Op, const float* __restrict__ Lp,
    unsigned short* __restrict__ X)
{
    size_t i = ((size_t)blockIdx.x * 256 + threadIdx.x) * 4;
    int c = (int)(i % DIM);
    size_t tok = i / DIM;
    int b = (int)(tok >> 12), tl = (int)(tok & 4095);
    int h = c >> 6;
    float l0 = Lp[((size_t)(b * NH + h)) * 4096 + tl];
    float l1 = Lp[((size_t)24 + b * NH + h) * 4096 + tl];
    float inv = 1.f / (l0 + l1);
    floatx4 a = *(const floatx4*)(Op + i);
    floatx4 d = *(const floatx4*)(Op + TELEM + i);
    us4 pkv;
    pkv[0] = f2bf((a[0] + d[0]) * inv);
    pkv[1] = f2bf((a[1] + d[1]) * inv);
    pkv[2] = f2bf((a[2] + d[2]) * inv);
    pkv[3] = f2bf((a[3] + d[3]) * inv);
    *(us4*)(X + i) = pkv;
}

extern "C" void kernel_launch(void* const* d_in, const int* in_sizes, int n_in,
                              void* d_out, int out_size, void* d_ws, size_t ws_size,
                              hipStream_t stream) {
    const float* query = (const float*)d_in[0];
    const float* key   = (const float*)d_in[1];
    const float* value = (const float*)d_in[2];
    const float* Wq    = (const float*)d_in[3];
    const float* Wk    = (const float*)d_in[4];
    const float* bk    = (const float*)d_in[5];
    const float* Wv    = (const float*)d_in[6];
    const float* Wp    = (const float*)d_in[7];
    const float* bp    = (const float*)d_in[8];
    float* out = (float*)d_out;

    unsigned short* ws = (unsigned short*)d_ws;
    unsigned short* Wqb = ws;
    unsigned short* Wkb = Wqb + WELEM;
    unsigned short* Wvb = Wkb + WELEM;
    unsigned short* Wpb = Wvb + WELEM;
    unsigned short* Qp  = Wpb + WELEM;
    unsigned short* Kp  = Qp + TELEM;
    unsigned short* Vtp = Kp + TELEM;
    unsigned short* Xp  = Vtp + TELEM;
    unsigned short* tail = Xp + TELEM;

    const size_t base_b = ((size_t)4 * WELEM + 4 * TELEM) * 2;
    const size_t cvt_b  = (size_t)3 * TELEM * 2;
    const size_t part_b = (size_t)2 * TELEM * 4 + (size_t)LELEM * 4;

    bool cvt_ok, split_ok;
    unsigned short* Qbf = tail;
    float* Opart;
    if (ws_size >= base_b + cvt_b + part_b)      { cvt_ok = true;  split_ok = true;  Opart = (float*)(tail + 3 * TELEM); }
    else if (ws_size >= base_b + part_b)         { cvt_ok = false; split_ok = true;  Opart = (float*)tail; }
    else if (ws_size >= base_b + cvt_b)          { cvt_ok = true;  split_ok = false; Opart = nullptr; }
    else                                         { cvt_ok = false; split_ok = false; Opart = nullptr; }
    float* Lpart = Opart ? Opart + (size_t)2 * TELEM : nullptr;
    unsigned short* Kbf = Qbf + TELEM;
    unsigned short* Vbf = Kbf + TELEM;

    cvt_w<<<dim3(4 * WELEM / 8 / 256), 256, 0, stream>>>(Wq, Wk, Wv, Wp, Wqb);
    if (cvt_ok) {
        cvt_in<<<dim3(3 * TELEM / 8 / 256), 256, 0, stream>>>(query, key, value, Qbf);
        qkv_gemm<1><<<dim3(64, 6, 3), 256, 0, stream>>>(Qbf, Kbf, Vbf, Wqb, Wkb, Wvb, bk, Qp, Kp, Vtp);
    } else {
        qkv_gemm<0><<<dim3(64, 6, 3), 256, 0, stream>>>(query, key, value, Wqb, Wkb, Wvb, bk, Qp, Kp, Vtp);
    }
    if (split_ok) {
        attn_kernel<2><<<dim3(32, 24, 2), 128, 0, stream>>>(Qp, Kp, Vtp, nullptr, Opart, Lpart);
        merge_kernel<<<dim3(TELEM / 4 / 256), 256, 0, stream>>>(Opart, Lpart, Xp);
    } else {
        attn_kernel<1><<<dim3(32, 24), 128, 0, stream>>>(Qp, Kp, Vtp, Xp, nullptr, nullptr);
    }
    out_gemm<<<dim3(64, 6), 256, 0, stream>>>(Xp, Wpb, bp, out);
}

// Round 7
// 333.363 us; speedup vs baseline: 3.8175x; 1.1014x over previous
//
#include <hip/hip_runtime.h>
#include <hip/hip_bf16.h>

// Round 7: attn = R4 body + double-buffered LDS staging, ONE barrier/iter:
//   barrier -> ds_read frags(buf t) -> issue gl2lds(t+1 -> other buf) -> compute
// Prefetch is issued ~compute-length before the next barrier's vmcnt drain ->
// L2/HBM latency hidden. Split/merge from R6 reverted (bought nothing).
// Packed bf16 cvt (v_cvt_pk_bf16_f32) replaces manual 3-op RNE packing.

#define DIM 768
#define NH 12
#define HD 64
#define NTOK 4096
#define WELEM 589824u      // 768*768
#define TELEM 6291456u     // 2*4096*768

typedef short bf16x8 __attribute__((ext_vector_type(8)));
typedef float floatx4 __attribute__((ext_vector_type(4)));
typedef unsigned short us4 __attribute__((ext_vector_type(4)));

__device__ __forceinline__ float bf2f(unsigned short u) {
    union { unsigned int i; float f; } v; v.i = ((unsigned int)u) << 16; return v.f;
}
__device__ __forceinline__ unsigned short f2bf(float f) {
    union { float f; unsigned int i; } v; v.f = f;
    unsigned int r = v.i + 0x7fffu + ((v.i >> 16) & 1u);
    return (unsigned short)(r >> 16);
}
// pack 2 floats -> 2 bf16 in one VGPR (v_cvt_pk_bf16_f32 on gfx950)
__device__ __forceinline__ unsigned int packbf(float a, float b) {
    __hip_bfloat162 h = __float22bfloat162_rn(make_float2(a, b));
    union { __hip_bfloat162 h; unsigned int u; } cv; cv.h = h; return cv.u;
}
__device__ __forceinline__ void gl2lds16(const unsigned short* g, unsigned short* l) {
    __builtin_amdgcn_global_load_lds(
        (const __attribute__((address_space(1))) unsigned int*)g,
        (__attribute__((address_space(3))) unsigned int*)l, 16, 0, 0);
}
__device__ __forceinline__ bf16x8 ld8_f32_to_bf16(const float* p) {
    floatx4 f0 = *(const floatx4*)p;
    floatx4 f1 = *(const floatx4*)(p + 4);
    union { unsigned int u[4]; bf16x8 v; } o;
    o.u[0] = packbf(f0[0], f0[1]);
    o.u[1] = packbf(f0[2], f0[3]);
    o.u[2] = packbf(f1[0], f1[1]);
    o.u[3] = packbf(f1[2], f1[3]);
    return o.v;
}

#if __has_builtin(__builtin_amdgcn_exp2f)
#define EXPFN(x) __builtin_amdgcn_exp2f(x)
#define QSCALE 0.18033688011f   /* 0.125 * log2(e) */
#else
#define EXPFN(x) __expf(x)
#define QSCALE 0.125f
#endif

// ---------------- fp32 -> bf16 converters ----------------
__global__ __launch_bounds__(256) void cvt_w(
    const float* __restrict__ a, const float* __restrict__ b,
    const float* __restrict__ c, const float* __restrict__ d,
    unsigned short* __restrict__ dst)
{
    size_t i = ((size_t)blockIdx.x * 256 + threadIdx.x) * 8;
    const float* s; size_t off;
    if (i < WELEM)            { s = a; off = i; }
    else if (i < 2u * WELEM)  { s = b; off = i - WELEM; }
    else if (i < 3u * WELEM)  { s = c; off = i - 2u * WELEM; }
    else                      { s = d; off = i - 3u * WELEM; }
    *(bf16x8*)(dst + i) = ld8_f32_to_bf16(s + off);
}

__global__ __launch_bounds__(256) void cvt_in(
    const float* __restrict__ a, const float* __restrict__ b,
    const float* __restrict__ c, unsigned short* __restrict__ dst)
{
    size_t i = ((size_t)blockIdx.x * 256 + threadIdx.x) * 8;
    const float* s; size_t off;
    if (i < TELEM)            { s = a; off = i; }
    else if (i < 2u * TELEM)  { s = b; off = i - TELEM; }
    else                      { s = c; off = i - 2u * TELEM; }
    *(bf16x8*)(dst + i) = ld8_f32_to_bf16(s + off);
}

// ---------------------------------------------------------------------------
// 128x128 tile GEMM, BK=64, XOR chunk swizzle (unchanged from R3/R4).
// ---------------------------------------------------------------------------
template <int A_IS_BF16>
__device__ __forceinline__ void gemm128(
    const void* __restrict__ Av, const unsigned short* __restrict__ W,
    const float* __restrict__ bias, void* __restrict__ Cv,
    int has_bias, int do_gelu, int trans, int out_f32)
{
    __shared__ unsigned short As[128 * 64];
    __shared__ unsigned short Bs[128 * 64];
    const int m0 = blockIdx.x * 128, n0 = blockIdx.y * 128;
    const int tid = threadIdx.x;
    const int w = tid >> 6, l = tid & 63;
    const int g = l >> 4, r16 = l & 15;
    const int wm = w >> 1, wn = w & 1;
    const int ro = l >> 3, c = l & 7;
    const int cswz = ((c ^ ro) & 7) * 8;

    floatx4 acc[4][4];
#pragma unroll
    for (int i = 0; i < 4; i++)
#pragma unroll
        for (int j = 0; j < 4; j++) acc[i][j] = (floatx4){0.f, 0.f, 0.f, 0.f};

    for (int k0 = 0; k0 < DIM; k0 += 64) {
#pragma unroll
        for (int q = 0; q < 4; q++) {
            int rbase = w * 32 + q * 8;
            if (A_IS_BF16) {
                gl2lds16((const unsigned short*)Av + (size_t)(m0 + rbase + ro) * DIM + k0 + cswz,
                         As + rbase * 64);
            } else {
                bf16x8 a = ld8_f32_to_bf16((const float*)Av + (size_t)(m0 + rbase + ro) * DIM + k0 + c * 8);
                *(bf16x8*)(As + (rbase + ro) * 64 + cswz) = a;
            }
            gl2lds16(W + (size_t)(n0 + rbase + ro) * DIM + k0 + cswz, Bs + rbase * 64);
        }
        __syncthreads();

#pragma unroll
        for (int kk = 0; kk < 2; kk++) {
            bf16x8 af[4], bfr[4];
            int x = r16 & 7;
#pragma unroll
            for (int i = 0; i < 4; i++)
                af[i] = *(const bf16x8*)(As + (wm * 64 + i * 16 + r16) * 64 + (((kk * 4 + g) ^ x) * 8));
#pragma unroll
            for (int j = 0; j < 4; j++)
                bfr[j] = *(const bf16x8*)(Bs + (wn * 64 + j * 16 + r16) * 64 + (((kk * 4 + g) ^ x) * 8));
#pragma unroll
            for (int i = 0; i < 4; i++)
#pragma unroll
                for (int j = 0; j < 4; j++)
                    acc[i][j] = __builtin_amdgcn_mfma_f32_16x16x32_bf16(af[i], bfr[j], acc[i][j], 0, 0, 0);
        }
        __syncthreads();
    }

    if (trans) {
        unsigned short* C = (unsigned short*)Cv;
#pragma unroll
        for (int i = 0; i < 4; i++) {
            int m = m0 + wm * 64 + i * 16 + g * 4;
            int b = m >> 12, tloc = m & 4095;
#pragma unroll
            for (int j = 0; j < 4; j++) {
                int n = n0 + wn * 64 + j * 16 + r16;
                int h = n >> 6, d = n & 63;
                union { unsigned int u[2]; us4 v; } pk;
                pk.u[0] = packbf(acc[i][j][0], acc[i][j][1]);
                pk.u[1] = packbf(acc[i][j][2], acc[i][j][3]);
                *(us4*)(C + ((size_t)(b * NH + h) * 64 + d) * NTOK + tloc) = pk.v;
            }
        }
    } else {
#pragma unroll
        for (int i = 0; i < 4; i++)
#pragma unroll
            for (int j = 0; j < 4; j++) {
                int n = n0 + wn * 64 + j * 16 + r16;
                float bv = has_bias ? bias[n] : 0.f;
#pragma unroll
                for (int r = 0; r < 4; r++) {
                    int m = m0 + wm * 64 + i * 16 + g * 4 + r;
                    float v = acc[i][j][r] + bv;
                    if (do_gelu) v = 0.5f * v * (1.f + erff(v * 0.70710678118f));
                    if (out_f32) ((float*)Cv)[(size_t)m * DIM + n] = v;
                    else ((unsigned short*)Cv)[(size_t)m * DIM + n] = f2bf(v);
                }
            }
    }
}

template <int A_IS_BF16>
__global__ __launch_bounds__(256) void qkv_gemm(
    const void* __restrict__ q_in, const void* __restrict__ k_in,
    const void* __restrict__ v_in,
    const unsigned short* __restrict__ Wq, const unsigned short* __restrict__ Wk,
    const unsigned short* __restrict__ Wv, const float* __restrict__ bk,
    unsigned short* __restrict__ Qo, unsigned short* __restrict__ Ko,
    unsigned short* __restrict__ Vto)
{
    int z = blockIdx.z;
    const void* A = (z == 0) ? q_in : (z == 1) ? k_in : v_in;
    const unsigned short* W = (z == 0) ? Wq : (z == 1) ? Wk : Wv;
    unsigned short* C = (z == 0) ? Qo : (z == 1) ? Ko : Vto;
    gemm128<A_IS_BF16>(A, W, bk, C, z == 1, z == 1, z == 2, 0);
}

__global__ __launch_bounds__(256) void out_gemm(
    const unsigned short* __restrict__ X, const unsigned short* __restrict__ Wp,
    const float* __restrict__ bp, float* __restrict__ out)
{
    gemm128<1>(X, Wp, bp, out, 1, 0, 0, 1);
}

// ---------------------------------------------------------------------------
// Flash attention R7: R4 per-wave structure (64 q-rows/wave, S^T/κ pipeline,
// no-max softmax) + double-buffered K/V LDS, one barrier per iteration.
// ---------------------------------------------------------------------------
__device__ __forceinline__ int swzf(int R) { return (R & 7) ^ ((R >> 2) & 6); }

__global__ __launch_bounds__(128, 2) void attn_kernel(
    const unsigned short* __restrict__ Q, const unsigned short* __restrict__ K,
    const unsigned short* __restrict__ Vt, unsigned short* __restrict__ X)
{
    __shared__ unsigned short Ks[2][64 * 64];
    __shared__ unsigned short Vs[2][64 * 64];
    const int qt = blockIdx.x, bh = blockIdx.y;
    const int b = bh / NH, h = bh % NH;
    const int tid = threadIdx.x;
    const int w = tid >> 6, l = tid & 63;
    const int g = l >> 4, r16 = l & 15;
    const int tokbase = b * NTOK;

    bf16x8 qfr[4][2];
#pragma unroll
    for (int qfi = 0; qfi < 4; qfi++) {
        int qrow = tokbase + qt * 128 + w * 64 + qfi * 16 + r16;
#pragma unroll
        for (int kk = 0; kk < 2; kk++) {
            bf16x8 t = *(const bf16x8*)(Q + (size_t)qrow * DIM + h * HD + kk * 32 + g * 8);
#pragma unroll
            for (int j = 0; j < 8; j++)
                t[j] = (short)f2bf(bf2f((unsigned short)t[j]) * QSCALE);
            qfr[qfi][kk] = t;
        }
    }

    int koff[4][2], voff[4][2];
#pragma unroll
    for (int ct = 0; ct < 4; ct++) {
        int krow = (ct >> 1) * 32 + (r16 >> 2) * 8 + (ct & 1) * 4 + (r16 & 3);
#pragma unroll
        for (int kk = 0; kk < 2; kk++)
            koff[ct][kk] = krow * 64 + (((kk * 4 + g) ^ swzf(krow)) * 8);
    }
#pragma unroll
    for (int dt = 0; dt < 4; dt++) {
        int vrow = dt * 16 + r16;
#pragma unroll
        for (int c = 0; c < 2; c++)
            voff[dt][c] = vrow * 64 + (((c * 4 + g) ^ swzf(vrow)) * 8);
    }

    int soff[8];
    const int srl = l >> 3, scc = l & 7;
    const int sstride = (w == 0) ? DIM : NTOK;
#pragma unroll
    for (int i = 0; i < 8; i++) {
        int row = i * 8 + srl;
        soff[i] = row * sstride + ((scc ^ swzf(row)) * 8);
    }
    const unsigned short* Kbase = K + (size_t)tokbase * DIM + h * HD;
    const unsigned short* Vbase = Vt + (size_t)bh * 64 * NTOK;

    floatx4 o[4][4];
#pragma unroll
    for (int qfi = 0; qfi < 4; qfi++)
#pragma unroll
        for (int dt = 0; dt < 4; dt++) o[qfi][dt] = (floatx4){0.f, 0.f, 0.f, 0.f};
    float lsum[4] = {0.f, 0.f, 0.f, 0.f};

    // prologue: stage tile 0 into buffer 0
    {
        const unsigned short* p = (w == 0) ? Kbase : Vbase;
        unsigned short* dst = (w == 0) ? Ks[0] : Vs[0];
#pragma unroll
        for (int i = 0; i < 8; i++) gl2lds16(p + soff[i], dst + i * 512);
    }

    for (int kt = 0; kt < NTOK / 64; kt++) {
        const int cur = kt & 1;
        __syncthreads();   // drains this wave's gl2lds -> tile kt visible to block

        // consume tile kt: fragment reads FIRST (program order before next issue)
        bf16x8 kr[4][2], vr[4][2];
#pragma unroll
        for (int ct = 0; ct < 4; ct++)
#pragma unroll
            for (int kk = 0; kk < 2; kk++)
                kr[ct][kk] = *(const bf16x8*)(Ks[cur] + koff[ct][kk]);
#pragma unroll
        for (int dt = 0; dt < 4; dt++)
#pragma unroll
            for (int c = 0; c < 2; c++)
                vr[dt][c] = *(const bf16x8*)(Vs[cur] + voff[dt][c]);

        // prefetch tile kt+1 into the other buffer (hidden behind compute)
        if (kt + 1 < NTOK / 64) {
            int keyg = (kt + 1) * 64;
            const unsigned short* p = (w == 0) ? (Kbase + (size_t)keyg * DIM)
                                               : (Vbase + keyg);
            unsigned short* dst = (w == 0) ? Ks[cur ^ 1] : Vs[cur ^ 1];
#pragma unroll
            for (int i = 0; i < 8; i++) gl2lds16(p + soff[i], dst + i * 512);
        }

#pragma unroll
        for (int qfi = 0; qfi < 4; qfi++) {
            floatx4 s[4];
#pragma unroll
            for (int ct = 0; ct < 4; ct++) {
                floatx4 zz = (floatx4){0.f, 0.f, 0.f, 0.f};
                zz = __builtin_amdgcn_mfma_f32_16x16x32_bf16(kr[ct][0], qfr[qfi][0], zz, 0, 0, 0);
                s[ct] = __builtin_amdgcn_mfma_f32_16x16x32_bf16(kr[ct][1], qfr[qfi][1], zz, 0, 0, 0);
            }
            float ls = 0.f;
#pragma unroll
            for (int ct = 0; ct < 4; ct++)
#pragma unroll
                for (int r = 0; r < 4; r++) {
                    float p2 = EXPFN(s[ct][r]);
                    s[ct][r] = p2;
                    ls += p2;
                }
            lsum[qfi] += ls;

            unsigned int pk[4][2];
#pragma unroll
            for (int ct = 0; ct < 4; ct++) {
                pk[ct][0] = packbf(s[ct][0], s[ct][1]);
                pk[ct][1] = packbf(s[ct][2], s[ct][3]);
            }
#pragma unroll
            for (int c = 0; c < 2; c++) {
                union { unsigned int u[4]; bf16x8 v; } bf;
                bf.u[0] = pk[2 * c][0]; bf.u[1] = pk[2 * c][1];
                bf.u[2] = pk[2 * c + 1][0]; bf.u[3] = pk[2 * c + 1][1];
#pragma unroll
                for (int dt = 0; dt < 4; dt++)
                    o[qfi][dt] = __builtin_amdgcn_mfma_f32_16x16x32_bf16(vr[dt][c], bf.v, o[qfi][dt], 0, 0, 0);
            }
        }
    }

#pragma unroll
    for (int qfi = 0; qfi < 4; qfi++) {
        lsum[qfi] += __shfl_xor(lsum[qfi], 16, 64);
        lsum[qfi] += __shfl_xor(lsum[qfi], 32, 64);
    }

#pragma unroll
    for (int qfi = 0; qfi < 4; qfi++) {
        float inv = 1.f / lsum[qfi];
        int tok = tokbase + qt * 128 + w * 64 + qfi * 16 + r16;
#pragma unroll
        for (int dt = 0; dt < 4; dt++) {
            union { unsigned int u[2]; us4 v; } pkv;
            pkv.u[0] = packbf(o[qfi][dt][0] * inv, o[qfi][dt][1] * inv);
            pkv.u[1] = packbf(o[qfi][dt][2] * inv, o[qfi][dt][3] * inv);
            *(us4*)(X + (size_t)tok * DIM + h * HD + dt * 16 + g * 4) = pkv.v;
        }
    }
}

extern "C" void kernel_launch(void* const* d_in, const int* in_sizes, int n_in,
                              void* d_out, int out_size, void* d_ws, size_t ws_size,
                              hipStream_t stream) {
    const float* query = (const float*)d_in[0];
    const float* key   = (const float*)d_in[1];
    const float* value = (const float*)d_in[2];
    const float* Wq    = (const float*)d_in[3];
    const float* Wk    = (const float*)d_in[4];
    const float* bk    = (const float*)d_in[5];
    const float* Wv    = (const float*)d_in[6];
    const float* Wp    = (const float*)d_in[7];
    const float* bp    = (const float*)d_in[8];
    float* out = (float*)d_out;

    unsigned short* ws = (unsigned short*)d_ws;
    unsigned short* Wqb = ws;
    unsigned short* Wkb = Wqb + WELEM;
    unsigned short* Wvb = Wkb + WELEM;
    unsigned short* Wpb = Wvb + WELEM;
    unsigned short* Qp  = Wpb + WELEM;
    unsigned short* Kp  = Qp + TELEM;
    unsigned short* Vtp = Kp + TELEM;
    unsigned short* Xp  = Vtp + TELEM;
    unsigned short* Qbf = Xp + TELEM;
    unsigned short* Kbf = Qbf + TELEM;
    unsigned short* Vbf = Kbf + TELEM;

    const size_t base_b = ((size_t)4 * WELEM + 4 * TELEM) * 2;
    const size_t cvt_b  = (size_t)3 * TELEM * 2;
    const bool cvt_ok = ws_size >= base_b + cvt_b;

    cvt_w<<<dim3(4 * WELEM / 8 / 256), 256, 0, stream>>>(Wq, Wk, Wv, Wp, Wqb);
    if (cvt_ok) {
        cvt_in<<<dim3(3 * TELEM / 8 / 256), 256, 0, stream>>>(query, key, value, Qbf);
        qkv_gemm<1><<<dim3(64, 6, 3), 256, 0, stream>>>(Qbf, Kbf, Vbf, Wqb, Wkb, Wvb, bk, Qp, Kp, Vtp);
    } else {
        qkv_gemm<0><<<dim3(64, 6, 3), 256, 0, stream>>>(query, key, value, Wqb, Wkb, Wvb, bk, Qp, Kp, Vtp);
    }
    attn_kernel<<<dim3(32, 24), 128, 0, stream>>>(Qp, Kp, Vtp, Xp);
    out_gemm<<<dim3(64, 6), 256, 0, stream>>>(Xp, Wpb, bp, out);
}